// Round 3
// baseline (138.381 us; speedup 1.0000x reference)
//
#include <hip/hip_runtime.h>
#include <math.h>

#define B_ 16
#define S_ 2048
#define IN_DIM 128
#define E2 6
#define E_ 3
#define OUT_DIM 64

// ws layout:
//   [0, B*S*4 floats)  : h padded to float4 (x,y,z,0)   = 524288 B
//   then 64 ints       : per batch {max_d2_bits, total, diag, vert}

// one wave per row: 64 lanes x float2 = 128 inputs. Block 0 also zeroes acc.
__global__ __launch_bounds__(256) void embed_kernel(
    const float* __restrict__ x, const float* __restrict__ w1,
    const float* __restrict__ b1, const float* __restrict__ w2,
    const float* __restrict__ b2, float* __restrict__ hws,
    int* __restrict__ acc)
{
    if (blockIdx.x == 0 && threadIdx.x < 64) acc[threadIdx.x] = 0;
    int wave = threadIdx.x >> 6;
    int lane = threadIdx.x & 63;
    int row  = blockIdx.x * 4 + wave;            // [0, B*S)
    const float2* x2 = (const float2*)(x + (size_t)row * IN_DIM);
    float2 xv = x2[lane];
    const float* w1a = w1 + (2 * lane) * E2;     // 12 contiguous floats
    float a[E2];
#pragma unroll
    for (int j = 0; j < E2; ++j)
        a[j] = xv.x * w1a[j] + xv.y * w1a[E2 + j];
#pragma unroll
    for (int j = 0; j < E2; ++j) {
#pragma unroll
        for (int off = 32; off >= 1; off >>= 1)
            a[j] += __shfl_xor(a[j], off, 64);
    }
    if (lane == 0) {
        float r[E2];
#pragma unroll
        for (int j = 0; j < E2; ++j) r[j] = fmaxf(a[j] + b1[j], 0.f);
        float h[E_];
#pragma unroll
        for (int e = 0; e < E_; ++e) {
            float s = b2[e];
#pragma unroll
            for (int j = 0; j < E2; ++j) s += r[j] * w2[j * E_ + e];
            h[e] = s;
        }
        ((float4*)hws)[row] = make_float4(h[0], h[1], h[2], 0.f);
    }
}

__device__ __forceinline__ float d2f(float4 a, float4 p) {
    float dx = a.x - p.x, dy = a.y - p.y, dz = a.z - p.z;
    return dx * dx + dy * dy + dz * dz;
}

// grid: B * 2 colBlocks * 32 rowSpans = 1024 blocks of 256.
// thread = 4 columns (stride 256); sweeps 64 uniform rows (scalar-loadable).
// Symmetry prune: max over row<=col pairs suffices (d2 symmetric, diag=0).
__global__ __launch_bounds__(256) void max_kernel(
    const float4* __restrict__ h4, int* __restrict__ acc)
{
    int bid = blockIdx.x;
    int b  = bid >> 6;
    int cb = (bid >> 5) & 1;
    int rb = bid & 31;
    int r0 = rb * 64;
    int c0 = cb * 1024;
    if (r0 > c0 + 1023) return;                  // all rows > all cols: mirrored elsewhere
    const float4* hb = h4 + (size_t)b * S_;
    float4 hj[4];
#pragma unroll
    for (int c = 0; c < 4; ++c) hj[c] = hb[c0 + c * 256 + threadIdx.x];
    float m = 0.f;
    for (int c8 = 0; c8 < 64; c8 += 8) {
        float4 buf[8];
#pragma unroll
        for (int k = 0; k < 8; ++k) buf[k] = hb[r0 + c8 + k];   // uniform -> s_load
#pragma unroll
        for (int c = 0; c < 4; ++c)
#pragma unroll
            for (int k = 0; k < 8; ++k)
                m = fmaxf(m, d2f(hj[c], buf[k]));
    }
#pragma unroll
    for (int off = 32; off >= 1; off >>= 1)
        m = fmaxf(m, __shfl_xor(m, off, 64));
    __shared__ float wmax[4];
    int lane = threadIdx.x & 63, wave = threadIdx.x >> 6;
    if (lane == 0) wmax[wave] = m;
    __syncthreads();
    if (threadIdx.x == 0) {
        float mm = fmaxf(fmaxf(wmax[0], wmax[1]), fmaxf(wmax[2], wmax[3]));
        atomicMax(&acc[b * 4 + 0], __float_as_int(mm));  // d2>=0: int order == float order
    }
}

__global__ __launch_bounds__(256) void stats_kernel(
    const float4* __restrict__ h4, const float* __restrict__ theta,
    int* __restrict__ acc)
{
    int bid = blockIdx.x;
    int b  = bid >> 6;
    int cb = (bid >> 5) & 1;
    int rb = bid & 31;
    int r0 = rb * 64;
    int c0 = cb * 1024;
    const float4* hb = h4 + (size_t)b * S_;
    int j[4];
    float4 hj[4];
#pragma unroll
    for (int c = 0; c < 4; ++c) {
        j[c] = c0 + c * 256 + threadIdx.x;
        hj[c] = hb[j[c]];
    }
    float maxd2 = __int_as_float(acc[b * 4 + 0]);
    float sig = 1.f / (1.f + expf(-theta[0]));
    float thr2 = sig * sig * maxd2;

    float4 pr = hb[(r0 > 0) ? (r0 - 1) : 0];             // uniform
    float4 nx = hb[(r0 + 64 < S_) ? (r0 + 64) : 0];      // uniform

    unsigned m0[4] = {0u, 0u, 0u, 0u}, m1[4] = {0u, 0u, 0u, 0u};
    for (int c8 = 0; c8 < 64; c8 += 8) {
        float4 buf[8];
#pragma unroll
        for (int k = 0; k < 8; ++k) buf[k] = hb[r0 + c8 + k];   // uniform -> s_load
#pragma unroll
        for (int c = 0; c < 4; ++c) {
#pragma unroll
            for (int k = 0; k < 8; ++k) {
                unsigned r = (d2f(hj[c], buf[k]) < thr2) ? 1u : 0u;
                int bit = c8 + k;
                if (bit < 32) m0[c] |= r << bit;
                else          m1[c] |= r << (bit - 32);
            }
        }
    }

    int total = 0, diag = 0, vert = 0;
#pragma unroll
    for (int c = 0; c < 4; ++c) {
        unsigned long long m = ((unsigned long long)m1[c] << 32) | m0[c];
        total += __popcll(m);
        unsigned long long prevbit =
            (r0 > 0) ? ((d2f(hj[c], pr) < thr2) ? 1ull : 0ull) : 0ull;
        unsigned long long nextbit =
            (r0 + 64 < S_) ? ((d2f(hj[c], nx) < thr2) ? 1ull : 0ull) : 0ull;
        // vertical run starts: R[i] & ~R[i-1] & R[i+1]
        unsigned long long notprev = ~((m << 1) | prevbit);
        vert += __popcll(m & notprev & ((m >> 1) | (nextbit << 63)));
        // diag band: rows s with j-s in [1,9] -> bits [j-9-r0, j-1-r0]
        int lo = j[c] - 9 - r0, hi = j[c] - 1 - r0;
        if (hi >= 0 && lo <= 63) {
            int l = lo < 0 ? 0 : lo;
            int h = hi > 63 ? 63 : hi;
            unsigned long long bandm = ((1ull << (h - l + 1)) - 1ull) << l;
            diag += __popcll(m & bandm);
        }
    }

#pragma unroll
    for (int off = 32; off >= 1; off >>= 1) {
        total += __shfl_xor(total, off, 64);
        diag  += __shfl_xor(diag,  off, 64);
        vert  += __shfl_xor(vert,  off, 64);
    }
    __shared__ int wsum[4][3];
    int lane = threadIdx.x & 63, wave = threadIdx.x >> 6;
    if (lane == 0) { wsum[wave][0] = total; wsum[wave][1] = diag; wsum[wave][2] = vert; }
    __syncthreads();
    if (threadIdx.x == 0) {
        int t = 0, d = 0, v = 0;
#pragma unroll
        for (int w = 0; w < 4; ++w) { t += wsum[w][0]; d += wsum[w][1]; v += wsum[w][2]; }
        atomicAdd(&acc[b * 4 + 1], t);
        atomicAdd(&acc[b * 4 + 2], d);
        atomicAdd(&acc[b * 4 + 3], v);
    }
}

__global__ void finalize_kernel(const int* __restrict__ acc,
    const float* __restrict__ w3, const float* __restrict__ b3,
    float* __restrict__ out)
{
    int idx = blockIdx.x * 256 + threadIdx.x;    // 0..1023
    if (idx >= B_ * OUT_DIM) return;
    int b = idx >> 6, o = idx & 63;
    float total = (float)acc[b * 4 + 1];
    float diag  = (float)acc[b * 4 + 2];
    float vert  = (float)acc[b * 4 + 3];
    float rr  = total / (float)(S_ * S_);
    float det = diag / (total + 1e-6f);
    float lam = vert / (total + 1e-6f);
    float entr = -total * logf(1.0f + 1e-6f);    // fp32 semantics (verified absmax 0.0)
    float r = b3[o] + rr  * w3[0 * OUT_DIM + o]
                    + det * w3[1 * OUT_DIM + o]
                    + lam * w3[2 * OUT_DIM + o]
                    + entr * w3[3 * OUT_DIM + o];
    out[idx] = fmaxf(r, 0.f);
}

extern "C" void kernel_launch(void* const* d_in, const int* in_sizes, int n_in,
                              void* d_out, int out_size, void* d_ws, size_t ws_size,
                              hipStream_t stream) {
    const float* x     = (const float*)d_in[0];
    const float* theta = (const float*)d_in[1];
    const float* w1    = (const float*)d_in[2];
    const float* b1    = (const float*)d_in[3];
    const float* w2    = (const float*)d_in[4];
    const float* b2    = (const float*)d_in[5];
    const float* w3    = (const float*)d_in[6];
    const float* b3    = (const float*)d_in[7];
    float* out = (float*)d_out;
    float* hws = (float*)d_ws;
    int* acc = (int*)((char*)d_ws + (size_t)B_ * S_ * 4 * sizeof(float));

    hipLaunchKernelGGL(embed_kernel, dim3(B_ * S_ / 4), dim3(256), 0, stream,
                       x, w1, b1, w2, b2, hws, acc);
    hipLaunchKernelGGL(max_kernel, dim3(B_ * 64), dim3(256), 0, stream,
                       (const float4*)hws, acc);
    hipLaunchKernelGGL(stats_kernel, dim3(B_ * 64), dim3(256), 0, stream,
                       (const float4*)hws, theta, acc);
    hipLaunchKernelGGL(finalize_kernel, dim3(4), dim3(256), 0, stream, acc, w3, b3, out);
}